// Round 6
// baseline (554.438 us; speedup 1.0000x reference)
//
#include <hip/hip_runtime.h>
#include <math.h>

#define NN 100000
#define NE 1600000
#define CH 128
#define TOTE (NE + NN)
#define EPSV 1e-5f
#define NB 98    // ceil(NN/1024)
#define NGB 1563 // ceil(NN/64)

typedef __attribute__((ext_vector_type(8))) short short8;
typedef __attribute__((ext_vector_type(4))) float floatx4;
typedef __attribute__((ext_vector_type(4))) int intx4;

__device__ __forceinline__ float lrelu(float v, float s) { return v < 0.f ? v * s : v; }

__device__ __forceinline__ unsigned short f2bf(float f) {
    unsigned int u = __float_as_uint(f);
    u += 0x7FFF + ((u >> 16) & 1);   // round-to-nearest-even
    return (unsigned short)(u >> 16);
}
__device__ __forceinline__ float bflo(unsigned int u) { return __uint_as_float(u << 16); }
__device__ __forceinline__ float bfhi(unsigned int u) { return __uint_as_float(u & 0xFFFF0000u); }

// ---------------- CSR build ----------------
__global__ void k_init(int* __restrict__ deg, int* __restrict__ cursor, float* __restrict__ stats) {
    int i = blockIdx.x * 256 + threadIdx.x;
    if (i < NN) { deg[i] = 1; cursor[i] = 0; }   // deg=1 accounts for the self-loop
    if (i < 4096) stats[i] = 0.f;
}

__global__ void k_count(const int* __restrict__ edges, int* __restrict__ deg) {
    int i = blockIdx.x * 256 + threadIdx.x;
    int base = i * 4;
    if (base < NE) {   // NE divisible by 4
        intx4 d = __builtin_nontemporal_load((const intx4*)&edges[NE + base]);
        atomicAdd(&deg[d.x], 1); atomicAdd(&deg[d.y], 1);
        atomicAdd(&deg[d.z], 1); atomicAdd(&deg[d.w], 1);
    }
}

__global__ void k_scan1(const int* __restrict__ deg, int* __restrict__ bsum, float* __restrict__ dinv) {
    __shared__ int red[256];
    int t = threadIdx.x;
    int base = blockIdx.x * 1024 + t * 4;
    int s = 0;
#pragma unroll
    for (int j = 0; j < 4; j++) {
        int i = base + j;
        if (i < NN) { int d = deg[i]; s += d; dinv[i] = rsqrtf((float)d); }
    }
    red[t] = s; __syncthreads();
    for (int off = 128; off > 0; off >>= 1) { if (t < off) red[t] += red[t + off]; __syncthreads(); }
    if (t == 0) bsum[blockIdx.x] = red[0];
}

// parallel exclusive scan of the 98 block sums (was a serial 1-thread loop)
__global__ void k_scan2(const int* __restrict__ bsum, int* __restrict__ boff) {
    __shared__ int sc[128];
    int t = threadIdx.x;
    int v = (t < NB) ? bsum[t] : 0;
    sc[t] = v; __syncthreads();
    for (int off = 1; off < 128; off <<= 1) {
        int u = (t >= off) ? sc[t - off] : 0;
        __syncthreads();
        sc[t] += u;
        __syncthreads();
    }
    if (t < NB) boff[t] = sc[t] - v;
}

__global__ void k_scan3(const int* __restrict__ deg, const int* __restrict__ boff, int* __restrict__ rowptr) {
    __shared__ int sc[256];
    int t = threadIdx.x;
    int base = blockIdx.x * 1024 + t * 4;
    int d[4];
#pragma unroll
    for (int j = 0; j < 4; j++) { int i = base + j; d[j] = (i < NN) ? deg[i] : 0; }
    int local = d[0] + d[1] + d[2] + d[3];
    sc[t] = local; __syncthreads();
    for (int off = 1; off < 256; off <<= 1) {
        int v = (t >= off) ? sc[t - off] : 0;
        __syncthreads();
        sc[t] += v;
        __syncthreads();
    }
    int run = sc[t] - local + boff[blockIdx.x];
#pragma unroll
    for (int j = 0; j < 4; j++) {
        int i = base + j;
        if (i < NN) { rowptr[i] = run; run += d[j]; }
    }
    if (blockIdx.x == 0 && t == 0) rowptr[NN] = TOTE;
}

// Two dst-range passes: active csr window 3.4 MB < 4 MiB per-XCD L2.
// Vectorized: 4 edges/thread via nontemporal int4 loads.
__global__ void k_fill(const int* __restrict__ edges, const int* __restrict__ rowptr,
                       int* __restrict__ cursor, int* __restrict__ csr, int lo, int hi) {
    int i = blockIdx.x * 256 + threadIdx.x;
    int base = i * 4;
    if (base < NE) {
        intx4 d = __builtin_nontemporal_load((const intx4*)&edges[NE + base]);
        intx4 s = __builtin_nontemporal_load((const intx4*)&edges[base]);
#pragma unroll
        for (int j = 0; j < 4; j++) {
            int dj = (j == 0) ? d.x : (j == 1) ? d.y : (j == 2) ? d.z : d.w;
            int sj = (j == 0) ? s.x : (j == 1) ? s.y : (j == 2) ? s.z : s.w;
            if (dj >= lo && dj < hi) {
                int pos = atomicAdd(&cursor[dj], 1);
                csr[rowptr[dj] + pos] = sj;
            }
        }
    } else {
        int v = i - NE / 4;
        if (v < NN && v >= lo && v < hi) {
            int pos = atomicAdd(&cursor[v], 1);
            csr[rowptr[v] + pos] = v;   // self-loop
        }
    }
}

// ---------------- W swizzle into MFMA B-fragment order (bf16) ----------------
__global__ void k_wswz(const float* __restrict__ W1, const float* __restrict__ Wg,
                       unsigned short* __restrict__ Wsw1, unsigned short* __restrict__ Wsw2) {
    int t = blockIdx.x * 256 + threadIdx.x;
    if (t >= 16384) return;
    int j = t & 7, lane = (t >> 3) & 63, ks = (t >> 9) & 3, nt = t >> 11;
    int k = ks * 32 + (lane >> 4) * 8 + j;
    int n = nt * 16 + (lane & 15);
    Wsw1[t] = f2bf(W1[k * CH + n]);
    Wsw2[t] = f2bf(Wg[k * CH + n]);
}

// ---------------- GEMM 1: H(bf16) = X @ W1 via MFMA; also emits Xb = bf16(X) ----------------
__launch_bounds__(256, 4)
__global__ void k_gemm1(const float* __restrict__ X, const unsigned short* __restrict__ Wsw,
                        unsigned short* __restrict__ H, unsigned short* __restrict__ Xb) {
    __shared__ __align__(16) short Xl[64 * 136];
    int t = threadIdx.x, wave = t >> 6, lane = t & 63;
    int row0 = blockIdx.x * 64;
    {   // stage X tile -> bf16 LDS (+ global Xb copy for gemm2)
        int r = t >> 2, q = t & 3;
        int gr = row0 + r;
        const float* Xr = X + (size_t)gr * CH;
#pragma unroll
        for (int j = 0; j < 4; j++) {
            int c0 = q * 32 + j * 8;
            float4 v0 = {0.f,0.f,0.f,0.f}, v1 = {0.f,0.f,0.f,0.f};
            if (gr < NN) { v0 = *(const float4*)&Xr[c0]; v1 = *(const float4*)&Xr[c0 + 4]; }
            short8 s;
            s[0]=f2bf(v0.x); s[1]=f2bf(v0.y); s[2]=f2bf(v0.z); s[3]=f2bf(v0.w);
            s[4]=f2bf(v1.x); s[5]=f2bf(v1.y); s[6]=f2bf(v1.z); s[7]=f2bf(v1.w);
            *(short8*)&Xl[r * 136 + c0] = s;
            if (gr < NN) *(short8*)&Xb[(size_t)gr * CH + c0] = s;
        }
    }
    __syncthreads();
    floatx4 acc[8];
#pragma unroll
    for (int nt = 0; nt < 8; nt++) acc[nt] = (floatx4){0.f, 0.f, 0.f, 0.f};
    int arow = wave * 16 + (lane & 15);
    int koff = (lane >> 4) * 8;
#pragma unroll
    for (int ks = 0; ks < 4; ks++) {
        short8 af = *(short8*)&Xl[arow * 136 + ks * 32 + koff];
#pragma unroll
        for (int nt = 0; nt < 8; nt++) {
            short8 bf = *(const short8*)&Wsw[((nt * 4 + ks) * 64 + lane) * 8];
            acc[nt] = __builtin_amdgcn_mfma_f32_16x16x32_bf16(af, bf, acc[nt], 0, 0, 0);
        }
    }
    int orow0 = row0 + wave * 16 + (lane >> 4) * 4;
    int ocol = lane & 15;
#pragma unroll
    for (int nt = 0; nt < 8; nt++) {
#pragma unroll
        for (int r = 0; r < 4; r++) {
            int row = orow0 + r;
            if (row < NN) H[(size_t)row * CH + nt * 16 + ocol] = f2bf(acc[nt][r]);
        }
    }
}

// ---------------- GCN aggregation: 8 edges/iter, 8-lane row slices (16 ch each) ----------------
__launch_bounds__(256)
__global__ void k_gcn_agg(const unsigned short* __restrict__ H, const int* __restrict__ csr,
                          const int* __restrict__ rowptr, const float* __restrict__ dinv,
                          const float* __restrict__ b1, unsigned short* __restrict__ T,
                          float* __restrict__ stats) {
    __shared__ float red_s[4][128], red_q[4][128];
    int t = threadIdx.x, wave = t >> 6, lane = t & 63;
    int g = lane >> 3, sl = lane & 7;
    float bias[16];
    {
        float4 b0 = *(const float4*)&b1[sl * 16];
        float4 b1v = *(const float4*)&b1[sl * 16 + 4];
        float4 b2 = *(const float4*)&b1[sl * 16 + 8];
        float4 b3 = *(const float4*)&b1[sl * 16 + 12];
        bias[0]=b0.x; bias[1]=b0.y; bias[2]=b0.z; bias[3]=b0.w;
        bias[4]=b1v.x; bias[5]=b1v.y; bias[6]=b1v.z; bias[7]=b1v.w;
        bias[8]=b2.x; bias[9]=b2.y; bias[10]=b2.z; bias[11]=b2.w;
        bias[12]=b3.x; bias[13]=b3.y; bias[14]=b3.z; bias[15]=b3.w;
    }
    float ssum[16], ssq[16];
#pragma unroll
    for (int j = 0; j < 16; j++) { ssum[j] = 0.f; ssq[j] = 0.f; }
    for (int node = blockIdx.x * 4 + wave; node < NN; node += gridDim.x * 4) {
        int beg = rowptr[node], end = rowptr[node + 1];
        float di = dinv[node];
        float acc[16];
#pragma unroll
        for (int j = 0; j < 16; j++) acc[j] = 0.f;
        int kk0 = beg + g;
        int s_cur = csr[kk0 < end ? kk0 : end - 1];
        for (int k = beg; k < end; k += 8) {
            int kn = k + 8 + g;
            int s_next = csr[kn < end ? kn : end - 1];
            bool valid = (k + g) < end;
            float w = valid ? dinv[s_cur] : 0.f;
            const unsigned short* Hp = &H[(size_t)s_cur * CH + sl * 16];
            uint4 u0 = *(const uint4*)Hp;
            uint4 u1 = *(const uint4*)(Hp + 8);
            acc[0] = fmaf(w, bflo(u0.x), acc[0]);  acc[1] = fmaf(w, bfhi(u0.x), acc[1]);
            acc[2] = fmaf(w, bflo(u0.y), acc[2]);  acc[3] = fmaf(w, bfhi(u0.y), acc[3]);
            acc[4] = fmaf(w, bflo(u0.z), acc[4]);  acc[5] = fmaf(w, bfhi(u0.z), acc[5]);
            acc[6] = fmaf(w, bflo(u0.w), acc[6]);  acc[7] = fmaf(w, bfhi(u0.w), acc[7]);
            acc[8] = fmaf(w, bflo(u1.x), acc[8]);  acc[9] = fmaf(w, bfhi(u1.x), acc[9]);
            acc[10] = fmaf(w, bflo(u1.y), acc[10]); acc[11] = fmaf(w, bfhi(u1.y), acc[11]);
            acc[12] = fmaf(w, bflo(u1.z), acc[12]); acc[13] = fmaf(w, bfhi(u1.z), acc[13]);
            acc[14] = fmaf(w, bflo(u1.w), acc[14]); acc[15] = fmaf(w, bfhi(u1.w), acc[15]);
            s_cur = s_next;
        }
#pragma unroll
        for (int j = 0; j < 16; j++) {
            acc[j] += __shfl_xor(acc[j], 8);
            acc[j] += __shfl_xor(acc[j], 16);
            acc[j] += __shfl_xor(acc[j], 32);
        }
        if (g == 0) {
            short8 sv0, sv1;
#pragma unroll
            for (int j = 0; j < 8; j++) {
                float tv = fmaf(di, acc[j], bias[j]);
                sv0[j] = (short)f2bf(tv);
                ssum[j] += tv; ssq[j] = fmaf(tv, tv, ssq[j]);
            }
#pragma unroll
            for (int j = 0; j < 8; j++) {
                float tv = fmaf(di, acc[8 + j], bias[8 + j]);
                sv1[j] = (short)f2bf(tv);
                ssum[8 + j] += tv; ssq[8 + j] = fmaf(tv, tv, ssq[8 + j]);
            }
            *(short8*)&T[(size_t)node * CH + sl * 16] = sv0;
            *(short8*)&T[(size_t)node * CH + sl * 16 + 8] = sv1;
        }
    }
    if (g == 0) {
#pragma unroll
        for (int j = 0; j < 16; j++) { red_s[wave][sl * 16 + j] = ssum[j]; red_q[wave][sl * 16 + j] = ssq[j]; }
    }
    __syncthreads();
    if (t < 128) {
        float s = 0.f, q = 0.f;
        for (int w2 = 0; w2 < 4; w2++) { s += red_s[w2][t]; q += red_q[w2][t]; }
        float* bank = stats + (blockIdx.x & 7) * 256;
        atomicAdd(&bank[t], s);
        atomicAdd(&bank[128 + t], q);
    }
}

// ---------------- GraphNorm finalize ----------------
__global__ void k_fin(const float* __restrict__ stats, const float* __restrict__ gw,
                      const float* __restrict__ gb, const float* __restrict__ gms,
                      float* __restrict__ alpha, float* __restrict__ beta) {
    int c = threadIdx.x;  // 128 threads
    float s = 0.f, q = 0.f;
    for (int b = 0; b < 8; b++) { s += stats[b * 256 + c]; q += stats[b * 256 + 128 + c]; }
    float mean = s * (1.f / NN);
    float ctr = gms[c] * mean;
    float var = q * (1.f / NN) - 2.f * ctr * mean + ctr * ctr;
    float al = gw[c] * rsqrtf(var + EPSV);
    alpha[c] = al;
    beta[c] = gb[c] - al * ctr;
}

// ---------------- GEMM 2 (fused): x1 = xb + lrelu(a1*T+b1); H=x1@Wg; a_s,a_d ----------------
__launch_bounds__(256, 4)
__global__ void k_gemm2(const unsigned short* __restrict__ Xb, const unsigned short* __restrict__ T,
                        const unsigned short* __restrict__ Wsw, const float* __restrict__ alpha,
                        const float* __restrict__ beta, const float* __restrict__ attS,
                        const float* __restrict__ attD, float* __restrict__ X1out,
                        unsigned short* __restrict__ H, float* __restrict__ a_s, float* __restrict__ a_d) {
    __shared__ __align__(16) short Xl[64 * 136];
    int t = threadIdx.x, wave = t >> 6, lane = t & 63;
    int row0 = blockIdx.x * 64;
    {   // fused staging: x1 = xb + lrelu(alpha*T+beta); store fp32 X1out; bf16 -> LDS
        int r = t >> 2, q = t & 3;
        int gr = row0 + r;
        size_t base = (size_t)gr * CH;
#pragma unroll
        for (int j = 0; j < 4; j++) {
            int c0 = q * 32 + j * 8;
            float v[8];
#pragma unroll
            for (int m = 0; m < 8; m++) v[m] = 0.f;
            if (gr < NN) {
                uint4 xu = *(const uint4*)&Xb[base + c0];
                uint4 tu = *(const uint4*)&T[base + c0];
                float4 al0 = *(const float4*)&alpha[c0];
                float4 al1 = *(const float4*)&alpha[c0 + 4];
                float4 be0 = *(const float4*)&beta[c0];
                float4 be1 = *(const float4*)&beta[c0 + 4];
                v[0] = bflo(xu.x) + lrelu(fmaf(al0.x, bflo(tu.x), be0.x), 0.01f);
                v[1] = bfhi(xu.x) + lrelu(fmaf(al0.y, bfhi(tu.x), be0.y), 0.01f);
                v[2] = bflo(xu.y) + lrelu(fmaf(al0.z, bflo(tu.y), be0.z), 0.01f);
                v[3] = bfhi(xu.y) + lrelu(fmaf(al0.w, bfhi(tu.y), be0.w), 0.01f);
                v[4] = bflo(xu.z) + lrelu(fmaf(al1.x, bflo(tu.z), be1.x), 0.01f);
                v[5] = bfhi(xu.z) + lrelu(fmaf(al1.y, bfhi(tu.z), be1.y), 0.01f);
                v[6] = bflo(xu.w) + lrelu(fmaf(al1.z, bflo(tu.w), be1.z), 0.01f);
                v[7] = bfhi(xu.w) + lrelu(fmaf(al1.w, bfhi(tu.w), be1.w), 0.01f);
                float4 o0 = {v[0], v[1], v[2], v[3]};
                float4 o1 = {v[4], v[5], v[6], v[7]};
                *(float4*)&X1out[base + c0] = o0;
                *(float4*)&X1out[base + c0 + 4] = o1;
            }
            short8 s;
#pragma unroll
            for (int m = 0; m < 8; m++) s[m] = (short)f2bf(v[m]);
            *(short8*)&Xl[r * 136 + c0] = s;
        }
    }
    __syncthreads();
    floatx4 acc[8];
#pragma unroll
    for (int nt = 0; nt < 8; nt++) acc[nt] = (floatx4){0.f, 0.f, 0.f, 0.f};
    int arow = wave * 16 + (lane & 15);
    int koff = (lane >> 4) * 8;
#pragma unroll
    for (int ks = 0; ks < 4; ks++) {
        short8 af = *(short8*)&Xl[arow * 136 + ks * 32 + koff];
#pragma unroll
        for (int nt = 0; nt < 8; nt++) {
            short8 bf = *(const short8*)&Wsw[((nt * 4 + ks) * 64 + lane) * 8];
            acc[nt] = __builtin_amdgcn_mfma_f32_16x16x32_bf16(af, bf, acc[nt], 0, 0, 0);
        }
    }
    int orow0 = row0 + wave * 16 + (lane >> 4) * 4;
    int ocol = lane & 15;
    float ps[4] = {0.f, 0.f, 0.f, 0.f}, pd[4] = {0.f, 0.f, 0.f, 0.f};
#pragma unroll
    for (int nt = 0; nt < 8; nt++) {
        float as_v = attS[nt * 16 + ocol];
        float ad_v = attD[nt * 16 + ocol];
#pragma unroll
        for (int r = 0; r < 4; r++) {
            int row = orow0 + r;
            if (row < NN) H[(size_t)row * CH + nt * 16 + ocol] = f2bf(acc[nt][r]);
            ps[r] = fmaf(acc[nt][r], as_v, ps[r]);
            pd[r] = fmaf(acc[nt][r], ad_v, pd[r]);
        }
    }
#pragma unroll
    for (int off = 1; off < 16; off <<= 1) {
#pragma unroll
        for (int r = 0; r < 4; r++) {
            ps[r] += __shfl_xor(ps[r], off);
            pd[r] += __shfl_xor(pd[r], off);
        }
    }
    if ((lane & 15) == 0) {
#pragma unroll
        for (int r = 0; r < 4; r++) {
            int row = orow0 + r;
            if (row < NN) { a_s[row] = ps[r]; a_d[row] = pd[r]; }
        }
    }
}

// ---------------- GAT aggregation: 8 edges/iter, single-pass softmax (|e| small) ----------------
__launch_bounds__(256)
__global__ void k_gat_agg(const unsigned short* __restrict__ H, const int* __restrict__ csr,
                          const int* __restrict__ rowptr, const float* __restrict__ a_s,
                          const float* __restrict__ a_d, const float* __restrict__ bg,
                          unsigned short* __restrict__ T, float* __restrict__ stats) {
    __shared__ float red_s[4][128], red_q[4][128];
    int t = threadIdx.x, wave = t >> 6, lane = t & 63;
    int g = lane >> 3, sl = lane & 7;
    float bias[16];
    {
        float4 b0 = *(const float4*)&bg[sl * 16];
        float4 b1v = *(const float4*)&bg[sl * 16 + 4];
        float4 b2 = *(const float4*)&bg[sl * 16 + 8];
        float4 b3 = *(const float4*)&bg[sl * 16 + 12];
        bias[0]=b0.x; bias[1]=b0.y; bias[2]=b0.z; bias[3]=b0.w;
        bias[4]=b1v.x; bias[5]=b1v.y; bias[6]=b1v.z; bias[7]=b1v.w;
        bias[8]=b2.x; bias[9]=b2.y; bias[10]=b2.z; bias[11]=b2.w;
        bias[12]=b3.x; bias[13]=b3.y; bias[14]=b3.z; bias[15]=b3.w;
    }
    float ssum[16], ssq[16];
#pragma unroll
    for (int j = 0; j < 16; j++) { ssum[j] = 0.f; ssq[j] = 0.f; }
    for (int node = blockIdx.x * 4 + wave; node < NN; node += gridDim.x * 4) {
        int beg = rowptr[node], end = rowptr[node + 1];
        float adI = a_d[node];
        float acc[16];
#pragma unroll
        for (int j = 0; j < 16; j++) acc[j] = 0.f;
        float den = 0.f;
        int kk0 = beg + g;
        int s_cur = csr[kk0 < end ? kk0 : end - 1];
        for (int k = beg; k < end; k += 8) {
            int kn = k + 8 + g;
            int s_next = csr[kn < end ? kn : end - 1];
            bool valid = (k + g) < end;
            float e = lrelu(a_s[s_cur] + adI, 0.2f);
            float wgt = valid ? __expf(e) : 0.f;
            den += wgt;
            const unsigned short* Hp = &H[(size_t)s_cur * CH + sl * 16];
            uint4 u0 = *(const uint4*)Hp;
            uint4 u1 = *(const uint4*)(Hp + 8);
            acc[0] = fmaf(wgt, bflo(u0.x), acc[0]);  acc[1] = fmaf(wgt, bfhi(u0.x), acc[1]);
            acc[2] = fmaf(wgt, bflo(u0.y), acc[2]);  acc[3] = fmaf(wgt, bfhi(u0.y), acc[3]);
            acc[4] = fmaf(wgt, bflo(u0.z), acc[4]);  acc[5] = fmaf(wgt, bfhi(u0.z), acc[5]);
            acc[6] = fmaf(wgt, bflo(u0.w), acc[6]);  acc[7] = fmaf(wgt, bfhi(u0.w), acc[7]);
            acc[8] = fmaf(wgt, bflo(u1.x), acc[8]);  acc[9] = fmaf(wgt, bfhi(u1.x), acc[9]);
            acc[10] = fmaf(wgt, bflo(u1.y), acc[10]); acc[11] = fmaf(wgt, bfhi(u1.y), acc[11]);
            acc[12] = fmaf(wgt, bflo(u1.z), acc[12]); acc[13] = fmaf(wgt, bfhi(u1.z), acc[13]);
            acc[14] = fmaf(wgt, bflo(u1.w), acc[14]); acc[15] = fmaf(wgt, bfhi(u1.w), acc[15]);
            s_cur = s_next;
        }
#pragma unroll
        for (int j = 0; j < 16; j++) {
            acc[j] += __shfl_xor(acc[j], 8);
            acc[j] += __shfl_xor(acc[j], 16);
            acc[j] += __shfl_xor(acc[j], 32);
        }
        den += __shfl_xor(den, 8);
        den += __shfl_xor(den, 16);
        den += __shfl_xor(den, 32);
        float inv = 1.f / den;
        if (g == 0) {
            short8 sv0, sv1;
#pragma unroll
            for (int j = 0; j < 8; j++) {
                float tv = fmaf(acc[j], inv, bias[j]);
                sv0[j] = (short)f2bf(tv);
                ssum[j] += tv; ssq[j] = fmaf(tv, tv, ssq[j]);
            }
#pragma unroll
            for (int j = 0; j < 8; j++) {
                float tv = fmaf(acc[8 + j], inv, bias[8 + j]);
                sv1[j] = (short)f2bf(tv);
                ssum[8 + j] += tv; ssq[8 + j] = fmaf(tv, tv, ssq[8 + j]);
            }
            *(short8*)&T[(size_t)node * CH + sl * 16] = sv0;
            *(short8*)&T[(size_t)node * CH + sl * 16 + 8] = sv1;
        }
    }
    if (g == 0) {
#pragma unroll
        for (int j = 0; j < 16; j++) { red_s[wave][sl * 16 + j] = ssum[j]; red_q[wave][sl * 16 + j] = ssq[j]; }
    }
    __syncthreads();
    if (t < 128) {
        float s = 0.f, q = 0.f;
        for (int w2 = 0; w2 < 4; w2++) { s += red_s[w2][t]; q += red_q[w2][t]; }
        float* bank = stats + (blockIdx.x & 7) * 256;
        atomicAdd(&bank[t], s);
        atomicAdd(&bank[128 + t], q);
    }
}

// ---------------- final: out = x1 + lrelu(a2*T2+b2)  (T2 bf16) ----------------
__global__ void k_final(const unsigned short* __restrict__ T, const float* __restrict__ alpha,
                        const float* __restrict__ beta, float* __restrict__ out) {
    size_t i = (size_t)(blockIdx.x * 256 + threadIdx.x) * 4;
    if (i >= (size_t)NN * CH) return;
    int c = (int)(i & (CH - 1));
    uint2 tu = *(const uint2*)&T[i];
    float4 av = *(const float4*)&alpha[c];
    float4 bv = *(const float4*)&beta[c];
    float4 o = *(float4*)&out[i];
    o.x += lrelu(fmaf(av.x, bflo(tu.x), bv.x), 0.01f);
    o.y += lrelu(fmaf(av.y, bfhi(tu.x), bv.y), 0.01f);
    o.z += lrelu(fmaf(av.z, bflo(tu.y), bv.z), 0.01f);
    o.w += lrelu(fmaf(av.w, bfhi(tu.y), bv.w), 0.01f);
    *(float4*)&out[i] = o;
}

extern "C" void kernel_launch(void* const* d_in, const int* in_sizes, int n_in,
                              void* d_out, int out_size, void* d_ws, size_t ws_size,
                              hipStream_t stream) {
    const float* x    = (const float*)d_in[0];
    const int*   edges= (const int*)d_in[1];
    const float* W1   = (const float*)d_in[2];
    const float* b1   = (const float*)d_in[3];
    const float* gw   = (const float*)d_in[4];
    const float* gb   = (const float*)d_in[5];
    const float* gms  = (const float*)d_in[6];
    const float* Wg   = (const float*)d_in[7];
    const float* bg   = (const float*)d_in[8];
    const float* attS = (const float*)d_in[9];
    const float* attD = (const float*)d_in[10];
    float* out = (float*)d_out;

    char* w = (char*)d_ws;
    size_t o = 0;
    unsigned short* H  = (unsigned short*)(w + o); o += (size_t)NN * CH * 2;  // 25.6 MB bf16
    unsigned short* T  = (unsigned short*)(w + o); o += (size_t)NN * CH * 2;  // 25.6 MB bf16
    unsigned short* Xb = (unsigned short*)(w + o); o += (size_t)NN * CH * 2;  // 25.6 MB bf16
    int*   csr    = (int*)(w + o);   o += (size_t)TOTE * 4;                   // 6.8 MB
    int*   rowptr = (int*)(w + o);   o += (size_t)(NN + 64) * 4;
    int*   deg    = (int*)(w + o);   o += (size_t)NN * 4;
    int*   cursor = (int*)(w + o);   o += (size_t)NN * 4;
    float* dinv   = (float*)(w + o); o += (size_t)NN * 4;
    float* a_s    = (float*)(w + o); o += (size_t)NN * 4;
    float* a_d    = (float*)(w + o); o += (size_t)NN * 4;
    int*   bsum   = (int*)(w + o);   o += 512;
    int*   boff   = (int*)(w + o);   o += 512;
    float* stats  = (float*)(w + o); o += 4096 * 4;
    float* alpha1 = (float*)(w + o); o += 512;
    float* beta1  = (float*)(w + o); o += 512;
    float* alpha2 = (float*)(w + o); o += 512;
    float* beta2  = (float*)(w + o); o += 512;
    unsigned short* Wsw1 = (unsigned short*)(w + o); o += 16384 * 2;
    unsigned short* Wsw2 = (unsigned short*)(w + o); o += 16384 * 2;

    k_init <<<(NN + 255) / 256, 256, 0, stream>>>(deg, cursor, stats);
    k_count<<<(NE / 4 + 255) / 256, 256, 0, stream>>>(edges, deg);
    k_scan1<<<NB, 256, 0, stream>>>(deg, bsum, dinv);
    k_scan2<<<1, 128, 0, stream>>>(bsum, boff);
    k_scan3<<<NB, 256, 0, stream>>>(deg, boff, rowptr);
    int fillb = (NE / 4 + NN + 255) / 256;
    k_fill <<<fillb, 256, 0, stream>>>(edges, rowptr, cursor, csr, 0, NN / 2);
    k_fill <<<fillb, 256, 0, stream>>>(edges, rowptr, cursor, csr, NN / 2, NN);
    k_wswz <<<64, 256, 0, stream>>>(W1, Wg, Wsw1, Wsw2);

    k_gemm1  <<<NGB, 256, 0, stream>>>(x, Wsw1, H, Xb);
    k_gcn_agg<<<2048, 256, 0, stream>>>(H, csr, rowptr, dinv, b1, T, stats);
    k_fin    <<<1, 128, 0, stream>>>(stats, gw, gb, gms, alpha1, beta1);

    k_gemm2  <<<NGB, 256, 0, stream>>>(Xb, T, Wsw2, alpha1, beta1, attS, attD, out, H, a_s, a_d);
    k_gat_agg<<<2048, 256, 0, stream>>>(H, csr, rowptr, a_s, a_d, bg, T, stats + 2048);
    k_fin    <<<1, 128, 0, stream>>>(stats + 2048, gw, gb, gms, alpha2, beta2);

    k_final<<<(NN * CH / 4 + 255) / 256, 256, 0, stream>>>(T, alpha2, beta2, out);
}